// Round 4
// baseline (426.594 us; speedup 1.0000x reference)
//
#include <hip/hip_runtime.h>
#include <math.h>

// N=100000 nodes, E=1000000 edges, D_IN=64, D_MODEL=64, H=4 x D=16.
// Packed node layout: per node, 16 chunks of 16 B; chunk c = bytes [16c,16c+16)
//   = { q[4c..4c+3] fp16 (8 B) | v[4c..4c+3] fp16 (8 B) }. Row = 256 B.

typedef _Float16 h2 __attribute__((ext_vector_type(2)));
typedef _Float16 half8 __attribute__((ext_vector_type(8)));
typedef float floatx4 __attribute__((ext_vector_type(4)));

#define SP_ROW 136  // fp16 per LDS row (272 B): +8 pad breaks pow-2 bank stride

// ---------------------------------------------------------------------------
// Kernel 0: prep. Blocks [0,32): Wt[n][k] = fp16 W[k][n] (n<64 -> Wqk col n,
// else Wv col n-64). Blocks [32,..): CSR rowptr binary search.  (UNCHANGED)
__global__ __launch_bounds__(256) void mhga_prep(
    const float* __restrict__ Wqk, const float* __restrict__ Wv,
    _Float16* __restrict__ Wt,
    const int* __restrict__ receivers, int* __restrict__ row_ptr,
    int N, int E)
{
    if ((int)blockIdx.x < 32) {
        const int idx = blockIdx.x * 256 + threadIdx.x;   // 0..8191
        const int n = idx >> 6, k = idx & 63;
        const float w = (n < 64) ? Wqk[k * 64 + n] : Wv[k * 64 + (n - 64)];
        Wt[idx] = (_Float16)w;
        return;
    }
    const int n = (blockIdx.x - 32) * 256 + threadIdx.x;
    if (n > N) return;
    int lo = 0, hi = E;
    while (lo < hi) {
        const int mid = (lo + hi) >> 1;
        if (receivers[mid] < n) lo = mid + 1; else hi = mid;
    }
    row_ptr[n] = lo;
}

// ---------------------------------------------------------------------------
// Kernel 1: MFMA fp16 projection -> packed fp16 q|v rows.  (UNCHANGED — control)
__global__ __launch_bounds__(256) void mhga_proj(
    const float* __restrict__ X, const _Float16* __restrict__ Wt,
    const float* __restrict__ bqk, const float* __restrict__ bv,
    unsigned char* __restrict__ packed, int N)
{
    __shared__ __align__(16) _Float16 sP[64 * SP_ROW];   // 17 KB repack tile
    const int t = threadIdx.x;
    const int w = t >> 6, lane = t & 63;
    const int ln = lane & 15, quad = lane >> 4;
    const int m0 = blockIdx.x * 64;

    // A fragments: A[m=ln][k=quad*8+j], k-halves 0 / 32. Direct f32 loads.
    const int arow = min(m0 + w * 16 + ln, N - 1);
    const float* xr = X + (size_t)arow * 64;
    const float4 xa = *(const float4*)(xr + quad * 8);
    const float4 xb = *(const float4*)(xr + quad * 8 + 4);
    const float4 xc = *(const float4*)(xr + 32 + quad * 8);
    const float4 xd = *(const float4*)(xr + 32 + quad * 8 + 4);
    const half8 a0 = { (_Float16)xa.x, (_Float16)xa.y, (_Float16)xa.z,
                       (_Float16)xa.w, (_Float16)xb.x, (_Float16)xb.y,
                       (_Float16)xb.z, (_Float16)xb.w };
    const half8 a1 = { (_Float16)xc.x, (_Float16)xc.y, (_Float16)xc.z,
                       (_Float16)xc.w, (_Float16)xd.x, (_Float16)xd.y,
                       (_Float16)xd.z, (_Float16)xd.w };

    // 8 output tiles: B[k][n], lane&15 = n-within-tile, k = quad*8+j.
    floatx4 acc[8];
#pragma unroll
    for (int tt = 0; tt < 8; ++tt) {
        const _Float16* wrow = Wt + (tt * 16 + ln) * 64;
        const half8 b0 = *(const half8*)(wrow + quad * 8);
        const half8 b1 = *(const half8*)(wrow + 32 + quad * 8);
        floatx4 c = {0.f, 0.f, 0.f, 0.f};
        c = __builtin_amdgcn_mfma_f32_16x16x32_f16(a0, b0, c, 0, 0, 0);
        c = __builtin_amdgcn_mfma_f32_16x16x32_f16(a1, b1, c, 0, 0, 0);
        acc[tt] = c;
    }

    // Repack: D row = quad*4+reg, col j = tt*16+ln. q col j -> fp16 idx
    // (j>>2)*8 + (j&3); v col j -> (j>>2)*8 + 4 + (j&3).
#pragma unroll
    for (int tt = 0; tt < 8; ++tt) {
        const float bt = (tt < 4) ? bqk[tt * 16 + ln] : bv[(tt - 4) * 16 + ln];
        const int j = (tt & 3) * 16 + ln;
        const int fidx = (j >> 2) * 8 + ((tt < 4) ? 0 : 4) + (j & 3);
#pragma unroll
        for (int r = 0; r < 4; ++r) {
            const int lrow = w * 16 + quad * 4 + r;
            sP[lrow * SP_ROW + fidx] = (_Float16)(acc[tt][r] + bt);
        }
    }

    // Wave-local coalesced copy: lane lt -> row w*16+(lt>>2), 64-B segment
    // (lt&3). In-order DS completion + compiler lgkmcnt ordering make the
    // write->read dependency safe within the wave (no barrier).
    const int crow = w * 16 + (lane >> 2);
    const int grow = m0 + crow;
    if (grow < N) {
        const _Float16* src = sP + crow * SP_ROW + (lane & 3) * 32;
        unsigned char* dst = packed + (size_t)grow * 256 + (lane & 3) * 64;
#pragma unroll
        for (int c = 0; c < 4; ++c)
            *(uint4*)(dst + c * 16) = *(const uint4*)(src + c * 8);
    }
}

// ---------------------------------------------------------------------------
// Kernel 2: fused attention + output projection.
// Round-4: NODE-PAIR per wave per lap (round-3's speculative pipeline blew
// FETCH 125->208 MB and regressed; this gets 2 gathers in flight with ZERO
// speculative loads). Nodes (2p, 2p+1) have adjacent CSR ranges -> one
// coalesced senders load covers both; the two gather chains are independent
// and interleaved -> 2x memory-level parallelism at identical traffic.
//  * sCtx folded into sAtt -> LDS 20480 B exactly -> 8 blocks/CU;
//    launch_bounds(256,8) pins VGPR <= 64.
//  * Epilogue: both nodes' matvecs share each sW load (half the LDS reads).
//  * Pair fallback (cntT > 64, never taken for Poisson(10) data): per-node
//    chunked accumulate, raw p -> attn_out, vmcnt(0) drain + volatile
//    in-place normalize (round-2 semantics).
__global__ __launch_bounds__(256, 8) void mhga_attn(
    const unsigned char* __restrict__ packed,
    const int* __restrict__ senders, const int* __restrict__ row_ptr,
    const float* __restrict__ Wout, const float* __restrict__ bout,
    float* __restrict__ out, float* __restrict__ attn_out, int N)
{
    __shared__ float sW[64 * 64];     // Wout[k][j]                     (16 KB)
    __shared__ float sAtt[4][256];    // p stage; [w][0..127] = ctx bcast (4 KB)
    const int t = threadIdx.x;
#pragma unroll
    for (int i = t * 4; i < 4096; i += 1024)
        *(float4*)(sW + i) = *(const float4*)(Wout + i);

    const int wave = t >> 6, lane = t & 63;
    const int g = lane >> 4, tl = lane & 15;   // edge-group, channel-lane
    const float bo = bout[lane];
    __syncthreads();   // the ONLY block-wide barrier

    const int P = (N + 1) >> 1;   // node pairs
    for (int pr = blockIdx.x * 4 + wave; pr < P; pr += gridDim.x * 4) {
        const int n0 = pr * 2, n1 = n0 + 1;
        const int e0 = row_ptr[n0];
        const int e1 = row_ptr[n1];                       // n1 <= N always
        const int e2 = (n1 < N) ? row_ptr[n1 + 1] : e1;
        const int cnt0 = e1 - e0, cnt1 = e2 - e1, cntT = e2 - e0;

        // Receiver q rows, channels 4tl..4tl+3 (head tl>>2).
        const uint4 q0pk = *(const uint4*)(packed + (size_t)n0 * 256 + tl * 16);
        const int n1c = min(n1, N - 1);
        const uint4 q1pk = *(const uint4*)(packed + (size_t)n1c * 256 + tl * 16);
        const h2 qa0 = __builtin_bit_cast(h2, q0pk.x);
        const h2 qa1 = __builtin_bit_cast(h2, q0pk.y);
        const h2 qb0 = __builtin_bit_cast(h2, q1pk.x);
        const h2 qb1 = __builtin_bit_cast(h2, q1pk.y);

        float l0 = 0.f, l1 = 0.f;
        float4 c0 = make_float4(0.f, 0.f, 0.f, 0.f);
        float4 c1 = make_float4(0.f, 0.f, 0.f, 0.f);
        const bool slow = (cntT > 64);

        if (!slow) {
            // ---- hot path: interleaved dual-node gathers, p staged in LDS ----
            int sid = 0;
            if (e0 + lane < e2) sid = senders[e0 + lane];   // both nodes, coalesced
            const int it0 = (cnt0 + 3) >> 2;
            const int it1 = (cnt1 + 3) >> 2;
            const int im = max(it0, it1);
            for (int i = 0; i < im; ++i) {
                const int idx = i * 4 + g;                 // per-node local edge
                const bool doA = (i < it0), doB = (i < it1);  // wave-uniform
                uint4 pkA, pkB;
                if (doA) {
                    const int sA = __shfl(sid, idx, 64);
                    pkA = *(const uint4*)(packed + (size_t)sA * 256 + tl * 16);
                }
                if (doB) {
                    const int sB = __shfl(sid, (cnt0 + idx) & 63, 64);
                    pkB = *(const uint4*)(packed + (size_t)sB * 256 + tl * 16);
                }
                if (doA) {
                    const h2 k0 = __builtin_bit_cast(h2, pkA.x);
                    const h2 k1 = __builtin_bit_cast(h2, pkA.y);
                    const h2 v0 = __builtin_bit_cast(h2, pkA.z);
                    const h2 v1 = __builtin_bit_cast(h2, pkA.w);
                    float d = __builtin_amdgcn_fdot2(qa0, k0, 0.f, false);
                    d = __builtin_amdgcn_fdot2(qa1, k1, d, false);
                    d += __shfl_xor(d, 1, 64);             // head-quad reduce
                    d += __shfl_xor(d, 2, 64);
                    float p = __expf(d);
                    p = (idx < cnt0) ? p : 0.f;
                    if ((tl & 3) == 0 && idx < cnt0)
                        sAtt[wave][idx * 4 + (tl >> 2)] = p;
                    l0 += p;
                    c0.x = fmaf(p, (float)v0.x, c0.x);
                    c0.y = fmaf(p, (float)v0.y, c0.y);
                    c0.z = fmaf(p, (float)v1.x, c0.z);
                    c0.w = fmaf(p, (float)v1.y, c0.w);
                }
                if (doB) {
                    const h2 k0 = __builtin_bit_cast(h2, pkB.x);
                    const h2 k1 = __builtin_bit_cast(h2, pkB.y);
                    const h2 v0 = __builtin_bit_cast(h2, pkB.z);
                    const h2 v1 = __builtin_bit_cast(h2, pkB.w);
                    float d = __builtin_amdgcn_fdot2(qb0, k0, 0.f, false);
                    d = __builtin_amdgcn_fdot2(qb1, k1, d, false);
                    d += __shfl_xor(d, 1, 64);
                    d += __shfl_xor(d, 2, 64);
                    float p = __expf(d);
                    p = (idx < cnt1) ? p : 0.f;
                    if ((tl & 3) == 0 && idx < cnt1)
                        sAtt[wave][(cnt0 + idx) * 4 + (tl >> 2)] = p;
                    l1 += p;
                    c1.x = fmaf(p, (float)v0.x, c1.x);
                    c1.y = fmaf(p, (float)v0.y, c1.y);
                    c1.z = fmaf(p, (float)v1.x, c1.z);
                    c1.w = fmaf(p, (float)v1.y, c1.w);
                }
            }
        } else {
            // ---- rare fallback: per-node chunked, raw p -> attn_out ----
            for (int m = 0; m < 2; ++m) {
                const int s0 = m ? e1 : e0, s1 = m ? e2 : e1;
                const h2 qq0 = m ? qb0 : qa0, qq1 = m ? qb1 : qa1;
                for (int base = s0; base < s1; base += 64) {
                    const int c2 = min(64, s1 - base);
                    int sid2 = 0;
                    if (base + lane < s1) sid2 = senders[base + lane];
                    const int it2 = (c2 + 3) >> 2;
                    for (int i = 0; i < it2; ++i) {
                        const int idx = i * 4 + g;
                        const int s = __shfl(sid2, idx, 64);
                        if (idx < c2) {
                            const uint4 pk =
                                *(const uint4*)(packed + (size_t)s * 256 + tl * 16);
                            const h2 k0 = __builtin_bit_cast(h2, pk.x);
                            const h2 k1 = __builtin_bit_cast(h2, pk.y);
                            const h2 v0 = __builtin_bit_cast(h2, pk.z);
                            const h2 v1 = __builtin_bit_cast(h2, pk.w);
                            float d = __builtin_amdgcn_fdot2(qq0, k0, 0.f, false);
                            d = __builtin_amdgcn_fdot2(qq1, k1, d, false);
                            d += __shfl_xor(d, 1, 64);
                            d += __shfl_xor(d, 2, 64);
                            const float p = __expf(d);
                            if ((tl & 3) == 0)
                                attn_out[(size_t)(base + idx) * 4 + (tl >> 2)] = p;
                            if (m == 0) {
                                l0 += p;
                                c0.x = fmaf(p, (float)v0.x, c0.x);
                                c0.y = fmaf(p, (float)v0.y, c0.y);
                                c0.z = fmaf(p, (float)v1.x, c0.z);
                                c0.w = fmaf(p, (float)v1.y, c0.w);
                            } else {
                                l1 += p;
                                c1.x = fmaf(p, (float)v0.x, c1.x);
                                c1.y = fmaf(p, (float)v0.y, c1.y);
                                c1.z = fmaf(p, (float)v1.x, c1.z);
                                c1.w = fmaf(p, (float)v1.y, c1.w);
                            }
                        }
                    }
                }
            }
        }

        // Merge the 4 edge-group partials (butterfly -> all lanes merged).
#pragma unroll
        for (int mask = 16; mask <= 32; mask <<= 1) {
            l0   += __shfl_xor(l0, mask, 64);
            l1   += __shfl_xor(l1, mask, 64);
            c0.x += __shfl_xor(c0.x, mask, 64);
            c0.y += __shfl_xor(c0.y, mask, 64);
            c0.z += __shfl_xor(c0.z, mask, 64);
            c0.w += __shfl_xor(c0.w, mask, 64);
            c1.x += __shfl_xor(c1.x, mask, 64);
            c1.y += __shfl_xor(c1.y, mask, 64);
            c1.z += __shfl_xor(c1.z, mask, 64);
            c1.w += __shfl_xor(c1.w, mask, 64);
        }
        const float inv0 = (l0 > 0.f) ? (1.f / l0) : 0.f;   // head = tl>>2
        const float inv1 = (l1 > 0.f) ? (1.f / l1) : 0.f;

        // Pass B: normalized attn. Head for flat idx f is f&3 = lane&3.
        const float lh0 = __shfl(l0, (lane & 3) << 2, 64);
        const float lh1 = __shfl(l1, (lane & 3) << 2, 64);
        const float iv0 = (lh0 > 0.f) ? (1.f / lh0) : 0.f;
        const float iv1 = (lh1 > 0.f) ? (1.f / lh1) : 0.f;
        if (!slow) {
            const int fT = cntT * 4, f0 = cnt0 * 4;
            for (int f = lane; f < fT; f += 64) {
                const float iv = (f < f0) ? iv0 : iv1;
                attn_out[e0 * 4 + f] = sAtt[wave][f] * iv;   // wave-local LDS
            }
        } else {
            __builtin_amdgcn_s_waitcnt(0x0F70);   // vmcnt(0): drain raw-p stores
            volatile const float* vp = attn_out;  // L1-bypass
            for (int f = e0 * 4 + lane; f < e2 * 4; f += 64) {
                const float iv = (f < e1 * 4) ? iv0 : iv1;
                attn_out[f] = vp[f] * iv;
            }
        }

        // ctx broadcast into sAtt[wave][0..127] (after pass B's reads: same-
        // wave in-order DS makes read-then-write safe without a barrier).
        if (g == 0) {
            *(float4*)(&sAtt[wave][tl * 4]) =
                make_float4(c0.x * inv0, c0.y * inv0, c0.z * inv0, c0.w * inv0);
        } else if (g == 1) {
            *(float4*)(&sAtt[wave][64 + tl * 4]) =
                make_float4(c1.x * inv1, c1.y * inv1, c1.z * inv1, c1.w * inv1);
        }

        // Epilogue: out[n][j] = bout[j] + sum_k ctx[k]*Wout[k][j], both nodes
        // sharing each sW load; 2 chains per node.
        const float* sC0 = &sAtt[wave][0];
        const float* sC1 = &sAtt[wave][64];
        float a0 = bo, a1 = 0.f, b0 = bo, b1 = 0.f;
#pragma unroll
        for (int k = 0; k < 64; k += 8) {
            const float4 x0 = *(const float4*)(sC0 + k);
            const float4 x1 = *(const float4*)(sC0 + k + 4);
            const float4 y0 = *(const float4*)(sC1 + k);
            const float4 y1 = *(const float4*)(sC1 + k + 4);
            float w;
            w = sW[(k + 0) * 64 + lane]; a0 = fmaf(x0.x, w, a0); b0 = fmaf(y0.x, w, b0);
            w = sW[(k + 1) * 64 + lane]; a0 = fmaf(x0.y, w, a0); b0 = fmaf(y0.y, w, b0);
            w = sW[(k + 2) * 64 + lane]; a0 = fmaf(x0.z, w, a0); b0 = fmaf(y0.z, w, b0);
            w = sW[(k + 3) * 64 + lane]; a0 = fmaf(x0.w, w, a0); b0 = fmaf(y0.w, w, b0);
            w = sW[(k + 4) * 64 + lane]; a1 = fmaf(x1.x, w, a1); b1 = fmaf(y1.x, w, b1);
            w = sW[(k + 5) * 64 + lane]; a1 = fmaf(x1.y, w, a1); b1 = fmaf(y1.y, w, b1);
            w = sW[(k + 6) * 64 + lane]; a1 = fmaf(x1.z, w, a1); b1 = fmaf(y1.z, w, b1);
            w = sW[(k + 7) * 64 + lane]; a1 = fmaf(x1.w, w, a1); b1 = fmaf(y1.w, w, b1);
        }
        out[(size_t)n0 * 64 + lane] = a0 + a1;
        if (n1 < N)
            out[(size_t)n1 * 64 + lane] = b0 + b1;
    }
}

// ---------------------------------------------------------------------------
extern "C" void kernel_launch(void* const* d_in, const int* in_sizes, int n_in,
                              void* d_out, int out_size, void* d_ws, size_t ws_size,
                              hipStream_t stream) {
    const float* nodes   = (const float*)d_in[0];
    const float* W_qk    = (const float*)d_in[1];
    const float* b_qk    = (const float*)d_in[2];
    const float* W_v     = (const float*)d_in[3];
    const float* b_v     = (const float*)d_in[4];
    const float* W_out   = (const float*)d_in[5];
    const float* b_out   = (const float*)d_in[6];
    const int* senders   = (const int*)d_in[7];
    const int* receivers = (const int*)d_in[8];

    const int N = in_sizes[0] / 64;  // 100000
    const int E = in_sizes[7];       // 1000000

    float* out      = (float*)d_out;
    float* attn_out = out + (size_t)N * 64;

    // Workspace: packed fp16 q|v (25.6MB) | rowptr | [spare] | Wt (16KB)
    unsigned char* packed = (unsigned char*)d_ws;
    int*   rowp = (int*)(packed + (size_t)N * 256);
    float* spare = (float*)(rowp + (((N + 1) + 3) & ~3));
    _Float16* Wt = (_Float16*)(spare + (size_t)E * 4);

    const int RB = (N + 1 + 255) / 256;       // rowptr blocks
    mhga_prep<<<32 + RB, 256, 0, stream>>>(W_qk, W_v, Wt, receivers, rowp, N, E);
    mhga_proj<<<(N + 63) / 64, 256, 0, stream>>>(nodes, Wt, b_qk, b_v,
                                                 packed, N);
    // Persistent: 2048 blocks = 8 blocks/CU (LDS 20480 B, VGPR pinned <=64);
    // waves grid-stride independently over node PAIRS.
    mhga_attn<<<2048, 256, 0, stream>>>(packed, senders, rowp,
                                        W_out, b_out, out, attn_out, N);
}

// Round 5
// 215.646 us; speedup vs baseline: 1.9782x; 1.9782x over previous
//
#include <hip/hip_runtime.h>
#include <math.h>

// N=100000 nodes, E=1000000 edges, D_IN=64, D_MODEL=64, H=4 x D=16.
// Packed node layout: per node, 16 chunks of 16 B; chunk c = bytes [16c,16c+16)
//   = { q[4c..4c+3] fp16 (8 B) | v[4c..4c+3] fp16 (8 B) }. Row = 256 B.

typedef _Float16 h2 __attribute__((ext_vector_type(2)));
typedef _Float16 half8 __attribute__((ext_vector_type(8)));
typedef float floatx4 __attribute__((ext_vector_type(4)));

#define SP_ROW 136  // fp16 per LDS row (272 B): +8 pad breaks pow-2 bank stride

// ---------------------------------------------------------------------------
// Kernel 0: prep. Blocks [0,32): Wt[n][k] = fp16 W[k][n] (n<64 -> Wqk col n,
// else Wv col n-64). Blocks [32,..): CSR rowptr binary search.  (UNCHANGED)
__global__ __launch_bounds__(256) void mhga_prep(
    const float* __restrict__ Wqk, const float* __restrict__ Wv,
    _Float16* __restrict__ Wt,
    const int* __restrict__ receivers, int* __restrict__ row_ptr,
    int N, int E)
{
    if ((int)blockIdx.x < 32) {
        const int idx = blockIdx.x * 256 + threadIdx.x;   // 0..8191
        const int n = idx >> 6, k = idx & 63;
        const float w = (n < 64) ? Wqk[k * 64 + n] : Wv[k * 64 + (n - 64)];
        Wt[idx] = (_Float16)w;
        return;
    }
    const int n = (blockIdx.x - 32) * 256 + threadIdx.x;
    if (n > N) return;
    int lo = 0, hi = E;
    while (lo < hi) {
        const int mid = (lo + hi) >> 1;
        if (receivers[mid] < n) lo = mid + 1; else hi = mid;
    }
    row_ptr[n] = lo;
}

// ---------------------------------------------------------------------------
// Kernel 1: MFMA fp16 projection -> packed fp16 q|v rows.  (UNCHANGED — control)
__global__ __launch_bounds__(256) void mhga_proj(
    const float* __restrict__ X, const _Float16* __restrict__ Wt,
    const float* __restrict__ bqk, const float* __restrict__ bv,
    unsigned char* __restrict__ packed, int N)
{
    __shared__ __align__(16) _Float16 sP[64 * SP_ROW];   // 17 KB repack tile
    const int t = threadIdx.x;
    const int w = t >> 6, lane = t & 63;
    const int ln = lane & 15, quad = lane >> 4;
    const int m0 = blockIdx.x * 64;

    // A fragments: A[m=ln][k=quad*8+j], k-halves 0 / 32. Direct f32 loads.
    const int arow = min(m0 + w * 16 + ln, N - 1);
    const float* xr = X + (size_t)arow * 64;
    const float4 xa = *(const float4*)(xr + quad * 8);
    const float4 xb = *(const float4*)(xr + quad * 8 + 4);
    const float4 xc = *(const float4*)(xr + 32 + quad * 8);
    const float4 xd = *(const float4*)(xr + 32 + quad * 8 + 4);
    const half8 a0 = { (_Float16)xa.x, (_Float16)xa.y, (_Float16)xa.z,
                       (_Float16)xa.w, (_Float16)xb.x, (_Float16)xb.y,
                       (_Float16)xb.z, (_Float16)xb.w };
    const half8 a1 = { (_Float16)xc.x, (_Float16)xc.y, (_Float16)xc.z,
                       (_Float16)xc.w, (_Float16)xd.x, (_Float16)xd.y,
                       (_Float16)xd.z, (_Float16)xd.w };

    // 8 output tiles: B[k][n], lane&15 = n-within-tile, k = quad*8+j.
    floatx4 acc[8];
#pragma unroll
    for (int tt = 0; tt < 8; ++tt) {
        const _Float16* wrow = Wt + (tt * 16 + ln) * 64;
        const half8 b0 = *(const half8*)(wrow + quad * 8);
        const half8 b1 = *(const half8*)(wrow + 32 + quad * 8);
        floatx4 c = {0.f, 0.f, 0.f, 0.f};
        c = __builtin_amdgcn_mfma_f32_16x16x32_f16(a0, b0, c, 0, 0, 0);
        c = __builtin_amdgcn_mfma_f32_16x16x32_f16(a1, b1, c, 0, 0, 0);
        acc[tt] = c;
    }

    // Repack: D row = quad*4+reg, col j = tt*16+ln. q col j -> fp16 idx
    // (j>>2)*8 + (j&3); v col j -> (j>>2)*8 + 4 + (j&3).
#pragma unroll
    for (int tt = 0; tt < 8; ++tt) {
        const float bt = (tt < 4) ? bqk[tt * 16 + ln] : bv[(tt - 4) * 16 + ln];
        const int j = (tt & 3) * 16 + ln;
        const int fidx = (j >> 2) * 8 + ((tt < 4) ? 0 : 4) + (j & 3);
#pragma unroll
        for (int r = 0; r < 4; ++r) {
            const int lrow = w * 16 + quad * 4 + r;
            sP[lrow * SP_ROW + fidx] = (_Float16)(acc[tt][r] + bt);
        }
    }

    // Wave-local coalesced copy: lane lt -> row w*16+(lt>>2), 64-B segment
    // (lt&3). In-order DS completion + compiler lgkmcnt ordering make the
    // write->read dependency safe within the wave (no barrier).
    const int crow = w * 16 + (lane >> 2);
    const int grow = m0 + crow;
    if (grow < N) {
        const _Float16* src = sP + crow * SP_ROW + (lane & 3) * 32;
        unsigned char* dst = packed + (size_t)grow * 256 + (lane & 3) * 64;
#pragma unroll
        for (int c = 0; c < 4; ++c)
            *(uint4*)(dst + c * 16) = *(const uint4*)(src + c * 8);
    }
}

// ---------------------------------------------------------------------------
// Kernel 2: fused attention + output projection.
// Round-5 = round-2 base (verified best: 86.4 us attn, FETCH 125 MB) with
// EXACTLY three deltas, no other changes:
//  (a) sCtx folded into sAtt[wave][0..63] (reused after pass B's reads;
//      same-wave in-order DS makes read->write->read safe, verified in r3)
//      -> LDS = 16384 + 4096 = 20480 B exactly -> 8 blocks/CU (was 7).
//  (b) grid 2048 = 8 blocks/CU exact residency.
//  (c) epilogue split into 4 accumulator chains (64-deep -> 4x16).
// NO __launch_bounds__ min-waves forcing (r3/r4 showed (256,8) + extra state
// => scratch spills: WRITE_SIZE exploded 41->727 MB). VGPR ~36 naturally.
__global__ __launch_bounds__(256) void mhga_attn(
    const unsigned char* __restrict__ packed,
    const int* __restrict__ senders, const int* __restrict__ row_ptr,
    const float* __restrict__ Wout, const float* __restrict__ bout,
    float* __restrict__ out, float* __restrict__ attn_out, int N)
{
    __shared__ float sW[64 * 64];     // Wout[k][j]                    (16 KB)
    __shared__ float sAtt[4][256];    // p stage; [w][0..63] = ctx bcast (4 KB)
    const int t = threadIdx.x;
#pragma unroll
    for (int i = t * 4; i < 4096; i += 1024)
        *(float4*)(sW + i) = *(const float4*)(Wout + i);

    const int wave = t >> 6, lane = t & 63;
    const int g = lane >> 4, tl = lane & 15;   // edge-group, channel-lane
    const float bo = bout[lane];
    __syncthreads();   // the ONLY block-wide barrier

    for (int n = blockIdx.x * 4 + wave; n < N; n += gridDim.x * 4) {
        const int e0 = row_ptr[n];
        const int e1 = row_ptr[n + 1];
        const int cnt = e1 - e0;

        float l = 0.f;
        float4 ctx = make_float4(0.f, 0.f, 0.f, 0.f);
        const uint4 qpk = *(const uint4*)(packed + (size_t)n * 256 + tl * 16);
        const h2 q0 = __builtin_bit_cast(h2, qpk.x);
        const h2 q1 = __builtin_bit_cast(h2, qpk.y);

        if (cnt <= 64) {
            // ---- hot path: one 64-edge chunk, p staged in wave-local LDS ----
            int sid = 0;
            if (e0 + lane < e1) sid = senders[e0 + lane];   // coalesced
            const int iters = (cnt + 3) >> 2;
            for (int i = 0; i < iters; ++i) {
                const int idx = i * 4 + g;          // this group's edge
                const int s = __shfl(sid, idx, 64); // row 0 for tail slots
                const uint4 pk =
                    *(const uint4*)(packed + (size_t)s * 256 + tl * 16);
                const h2 k0 = __builtin_bit_cast(h2, pk.x);
                const h2 k1 = __builtin_bit_cast(h2, pk.y);
                const h2 v0 = __builtin_bit_cast(h2, pk.z);
                const h2 v1 = __builtin_bit_cast(h2, pk.w);
                float d = __builtin_amdgcn_fdot2(q0, k0, 0.f, false);
                d = __builtin_amdgcn_fdot2(q1, k1, d, false);
                d += __shfl_xor(d, 1, 64);          // head-group reduce
                d += __shfl_xor(d, 2, 64);
                float p = __expf(d);
                p = (idx < cnt) ? p : 0.f;          // cndmask, no branch
                if ((tl & 3) == 0)
                    sAtt[wave][idx * 4 + (tl >> 2)] = p;   // conflict-free
                l += p;
                ctx.x = fmaf(p, (float)v0.x, ctx.x);
                ctx.y = fmaf(p, (float)v0.y, ctx.y);
                ctx.z = fmaf(p, (float)v1.x, ctx.z);
                ctx.w = fmaf(p, (float)v1.y, ctx.w);
            }
        } else {
            // ---- rare fallback: raw p -> attn_out, normalize in place ----
            for (int base = e0; base < e1; base += 64) {
                const int c2 = min(64, e1 - base);
                int sid2 = 0;
                if (base + lane < e1) sid2 = senders[base + lane];
                const int it2 = (c2 + 3) >> 2;
                for (int i = 0; i < it2; ++i) {
                    const int idx = i * 4 + g;
                    const int s = __shfl(sid2, idx, 64);
                    if (idx < c2) {
                        const uint4 pk =
                            *(const uint4*)(packed + (size_t)s * 256 + tl * 16);
                        const h2 k0 = __builtin_bit_cast(h2, pk.x);
                        const h2 k1 = __builtin_bit_cast(h2, pk.y);
                        const h2 v0 = __builtin_bit_cast(h2, pk.z);
                        const h2 v1 = __builtin_bit_cast(h2, pk.w);
                        float d = __builtin_amdgcn_fdot2(q0, k0, 0.f, false);
                        d = __builtin_amdgcn_fdot2(q1, k1, d, false);
                        d += __shfl_xor(d, 1, 64);
                        d += __shfl_xor(d, 2, 64);
                        const float p = __expf(d);
                        if ((tl & 3) == 0)
                            attn_out[(size_t)(base + idx) * 4 + (tl >> 2)] = p;
                        l += p;
                        ctx.x = fmaf(p, (float)v0.x, ctx.x);
                        ctx.y = fmaf(p, (float)v0.y, ctx.y);
                        ctx.z = fmaf(p, (float)v1.x, ctx.z);
                        ctx.w = fmaf(p, (float)v1.y, ctx.w);
                    }
                }
            }
        }

        // Sum the 4 edge-group partials (butterfly -> all lanes merged).
#pragma unroll
        for (int mask = 16; mask <= 32; mask <<= 1) {
            l     += __shfl_xor(l, mask, 64);
            ctx.x += __shfl_xor(ctx.x, mask, 64);
            ctx.y += __shfl_xor(ctx.y, mask, 64);
            ctx.z += __shfl_xor(ctx.z, mask, 64);
            ctx.w += __shfl_xor(ctx.w, mask, 64);
        }
        const float inv = (l > 0.f) ? (1.f / l) : 0.f;   // per-head (tl>>2)

        // Pass B: attn = p / l[head], head = f&3 = lane&3 (stride 64).
        const float lh = __shfl(l, (lane & 3) << 2, 64);
        const float invl = (lh > 0.f) ? (1.f / lh) : 0.f;
        if (cnt <= 64) {
            const int cnt4 = cnt * 4;
            for (int f = lane; f < cnt4; f += 64)
                attn_out[e0 * 4 + f] = sAtt[wave][f] * invl;   // wave-local LDS
        } else {
            __builtin_amdgcn_s_waitcnt(0x0F70);   // vmcnt(0): drain raw-p stores
            volatile const float* vp = attn_out;  // L1-bypass
            for (int f = e0 * 4 + lane; f < e1 * 4; f += 64)
                attn_out[f] = vp[f] * invl;
        }

        // ctx broadcast into sAtt[wave][0..63] (after pass B's reads: same-
        // wave in-order DS makes the read->write safe without a barrier).
        if (g == 0) {
            *(float4*)(&sAtt[wave][tl * 4]) =
                make_float4(ctx.x * inv, ctx.y * inv, ctx.z * inv, ctx.w * inv);
        }

        // Epilogue: out[n][j] = bout[j] + sum_k ctx[k]*Wout[k][j]; 4 chains.
        const float* sCtx = &sAtt[wave][0];
        float a0 = bo, a1 = 0.f, a2 = 0.f, a3 = 0.f;
#pragma unroll
        for (int k = 0; k < 64; k += 16) {
            const float4 c0 = *(const float4*)(sCtx + k);
            const float4 c1 = *(const float4*)(sCtx + k + 4);
            const float4 c2 = *(const float4*)(sCtx + k + 8);
            const float4 c3 = *(const float4*)(sCtx + k + 12);
            a0 = fmaf(c0.x, sW[(k + 0) * 64 + lane], a0);
            a0 = fmaf(c0.y, sW[(k + 1) * 64 + lane], a0);
            a0 = fmaf(c0.z, sW[(k + 2) * 64 + lane], a0);
            a0 = fmaf(c0.w, sW[(k + 3) * 64 + lane], a0);
            a1 = fmaf(c1.x, sW[(k + 4) * 64 + lane], a1);
            a1 = fmaf(c1.y, sW[(k + 5) * 64 + lane], a1);
            a1 = fmaf(c1.z, sW[(k + 6) * 64 + lane], a1);
            a1 = fmaf(c1.w, sW[(k + 7) * 64 + lane], a1);
            a2 = fmaf(c2.x, sW[(k + 8) * 64 + lane], a2);
            a2 = fmaf(c2.y, sW[(k + 9) * 64 + lane], a2);
            a2 = fmaf(c2.z, sW[(k + 10) * 64 + lane], a2);
            a2 = fmaf(c2.w, sW[(k + 11) * 64 + lane], a2);
            a3 = fmaf(c3.x, sW[(k + 12) * 64 + lane], a3);
            a3 = fmaf(c3.y, sW[(k + 13) * 64 + lane], a3);
            a3 = fmaf(c3.z, sW[(k + 14) * 64 + lane], a3);
            a3 = fmaf(c3.w, sW[(k + 15) * 64 + lane], a3);
        }
        out[(size_t)n * 64 + lane] = (a0 + a1) + (a2 + a3);
    }
}

// ---------------------------------------------------------------------------
extern "C" void kernel_launch(void* const* d_in, const int* in_sizes, int n_in,
                              void* d_out, int out_size, void* d_ws, size_t ws_size,
                              hipStream_t stream) {
    const float* nodes   = (const float*)d_in[0];
    const float* W_qk    = (const float*)d_in[1];
    const float* b_qk    = (const float*)d_in[2];
    const float* W_v     = (const float*)d_in[3];
    const float* b_v     = (const float*)d_in[4];
    const float* W_out   = (const float*)d_in[5];
    const float* b_out   = (const float*)d_in[6];
    const int* senders   = (const int*)d_in[7];
    const int* receivers = (const int*)d_in[8];

    const int N = in_sizes[0] / 64;  // 100000
    const int E = in_sizes[7];       // 1000000

    float* out      = (float*)d_out;
    float* attn_out = out + (size_t)N * 64;

    // Workspace: packed fp16 q|v (25.6MB) | rowptr | [spare] | Wt (16KB)
    unsigned char* packed = (unsigned char*)d_ws;
    int*   rowp = (int*)(packed + (size_t)N * 256);
    float* spare = (float*)(rowp + (((N + 1) + 3) & ~3));
    _Float16* Wt = (_Float16*)(spare + (size_t)E * 4);

    const int RB = (N + 1 + 255) / 256;       // rowptr blocks
    mhga_prep<<<32 + RB, 256, 0, stream>>>(W_qk, W_v, Wt, receivers, rowp, N, E);
    mhga_proj<<<(N + 63) / 64, 256, 0, stream>>>(nodes, Wt, b_qk, b_v,
                                                 packed, N);
    // Persistent: 2048 blocks = 8 blocks/CU (LDS 20480 B exactly, VGPR ~36);
    // waves grid-stride independently.
    mhga_attn<<<2048, 256, 0, stream>>>(packed, senders, rowp,
                                        W_out, b_out, out, attn_out, N);
}

// Round 6
// 192.189 us; speedup vs baseline: 2.2197x; 1.1221x over previous
//
#include <hip/hip_runtime.h>
#include <math.h>

// N=100000 nodes, E=1000000 edges, D_IN=64, D_MODEL=64, H=4 x D=16.
// Packed node layout: per node, 16 chunks of 16 B; chunk c = bytes [16c,16c+16)
//   = { q[4c..4c+3] fp16 (8 B) | v[4c..4c+3] fp16 (8 B) }. Row = 256 B.

typedef _Float16 h2 __attribute__((ext_vector_type(2)));
typedef _Float16 half8 __attribute__((ext_vector_type(8)));
typedef float floatx4 __attribute__((ext_vector_type(4)));

#define SP_ROW 136  // fp16 per LDS row (272 B): +8 pad breaks pow-2 bank stride

// ---------------------------------------------------------------------------
// Kernel 0: prep. Blocks [0,32): Wt[n][k] = fp16 W[k][n] (n<64 -> Wqk col n,
// else Wv col n-64). Blocks [32,..): CSR rowptr binary search.  (UNCHANGED)
__global__ __launch_bounds__(256) void mhga_prep(
    const float* __restrict__ Wqk, const float* __restrict__ Wv,
    _Float16* __restrict__ Wt,
    const int* __restrict__ receivers, int* __restrict__ row_ptr,
    int N, int E)
{
    if ((int)blockIdx.x < 32) {
        const int idx = blockIdx.x * 256 + threadIdx.x;   // 0..8191
        const int n = idx >> 6, k = idx & 63;
        const float w = (n < 64) ? Wqk[k * 64 + n] : Wv[k * 64 + (n - 64)];
        Wt[idx] = (_Float16)w;
        return;
    }
    const int n = (blockIdx.x - 32) * 256 + threadIdx.x;
    if (n > N) return;
    int lo = 0, hi = E;
    while (lo < hi) {
        const int mid = (lo + hi) >> 1;
        if (receivers[mid] < n) lo = mid + 1; else hi = mid;
    }
    row_ptr[n] = lo;
}

// ---------------------------------------------------------------------------
// Kernel 1: MFMA fp16 projection -> packed fp16 q|v rows.  (UNCHANGED — control)
__global__ __launch_bounds__(256) void mhga_proj(
    const float* __restrict__ X, const _Float16* __restrict__ Wt,
    const float* __restrict__ bqk, const float* __restrict__ bv,
    unsigned char* __restrict__ packed, int N)
{
    __shared__ __align__(16) _Float16 sP[64 * SP_ROW];   // 17 KB repack tile
    const int t = threadIdx.x;
    const int w = t >> 6, lane = t & 63;
    const int ln = lane & 15, quad = lane >> 4;
    const int m0 = blockIdx.x * 64;

    // A fragments: A[m=ln][k=quad*8+j], k-halves 0 / 32. Direct f32 loads.
    const int arow = min(m0 + w * 16 + ln, N - 1);
    const float* xr = X + (size_t)arow * 64;
    const float4 xa = *(const float4*)(xr + quad * 8);
    const float4 xb = *(const float4*)(xr + quad * 8 + 4);
    const float4 xc = *(const float4*)(xr + 32 + quad * 8);
    const float4 xd = *(const float4*)(xr + 32 + quad * 8 + 4);
    const half8 a0 = { (_Float16)xa.x, (_Float16)xa.y, (_Float16)xa.z,
                       (_Float16)xa.w, (_Float16)xb.x, (_Float16)xb.y,
                       (_Float16)xb.z, (_Float16)xb.w };
    const half8 a1 = { (_Float16)xc.x, (_Float16)xc.y, (_Float16)xc.z,
                       (_Float16)xc.w, (_Float16)xd.x, (_Float16)xd.y,
                       (_Float16)xd.z, (_Float16)xd.w };

    // 8 output tiles: B[k][n], lane&15 = n-within-tile, k = quad*8+j.
    floatx4 acc[8];
#pragma unroll
    for (int tt = 0; tt < 8; ++tt) {
        const _Float16* wrow = Wt + (tt * 16 + ln) * 64;
        const half8 b0 = *(const half8*)(wrow + quad * 8);
        const half8 b1 = *(const half8*)(wrow + 32 + quad * 8);
        floatx4 c = {0.f, 0.f, 0.f, 0.f};
        c = __builtin_amdgcn_mfma_f32_16x16x32_f16(a0, b0, c, 0, 0, 0);
        c = __builtin_amdgcn_mfma_f32_16x16x32_f16(a1, b1, c, 0, 0, 0);
        acc[tt] = c;
    }

    // Repack: D row = quad*4+reg, col j = tt*16+ln. q col j -> fp16 idx
    // (j>>2)*8 + (j&3); v col j -> (j>>2)*8 + 4 + (j&3).
#pragma unroll
    for (int tt = 0; tt < 8; ++tt) {
        const float bt = (tt < 4) ? bqk[tt * 16 + ln] : bv[(tt - 4) * 16 + ln];
        const int j = (tt & 3) * 16 + ln;
        const int fidx = (j >> 2) * 8 + ((tt < 4) ? 0 : 4) + (j & 3);
#pragma unroll
        for (int r = 0; r < 4; ++r) {
            const int lrow = w * 16 + quad * 4 + r;
            sP[lrow * SP_ROW + fidx] = (_Float16)(acc[tt][r] + bt);
        }
    }

    // Wave-local coalesced copy: lane lt -> row w*16+(lt>>2), 64-B segment
    // (lt&3). In-order DS completion + compiler lgkmcnt ordering make the
    // write->read dependency safe within the wave (no barrier).
    const int crow = w * 16 + (lane >> 2);
    const int grow = m0 + crow;
    if (grow < N) {
        const _Float16* src = sP + crow * SP_ROW + (lane & 3) * 32;
        unsigned char* dst = packed + (size_t)grow * 256 + (lane & 3) * 64;
#pragma unroll
        for (int c = 0; c < 4; ++c)
            *(uint4*)(dst + c * 16) = *(const uint4*)(src + c * 8);
    }
}

// ---------------------------------------------------------------------------
// Kernel 2: fused attention + output projection.
// Round-6 = EXACT round-2 base (verified best: 86.4 us attn, FETCH 125 MB,
// WRITE 41.6 MB, VGPR 36, occ 59%) + ONE change: the hot-path gather loop is
// 2-deep software-pipelined — gather i+1 is issued BEFORE consuming gather i,
// so the per-lap critical path drops from ~3 serialized L2-miss latencies to
// ~1 + pipeline fill. Identical address set (no speculation): traffic must
// stay at 125/41.6 MB. No __launch_bounds__ min-waves forcing (r3/r4 showed
// forced caps => scratch spill), grid 1792 = 7 blocks/CU exact (r5 showed
// grid > residency => serial tail), separate sCtx (r2 layout, LDS 21504).
__global__ __launch_bounds__(256) void mhga_attn(
    const unsigned char* __restrict__ packed,
    const int* __restrict__ senders, const int* __restrict__ row_ptr,
    const float* __restrict__ Wout, const float* __restrict__ bout,
    float* __restrict__ out, float* __restrict__ attn_out, int N)
{
    __shared__ float sW[64 * 64];    // Wout[k][j]               (16 KB)
    __shared__ float sCtx[4][64];    // per-wave normalized ctx  (1 KB)
    __shared__ float sAtt[4][256];   // per-wave p stage: 64 edges x 4 heads (4 KB)
    const int t = threadIdx.x;
#pragma unroll
    for (int i = t * 4; i < 4096; i += 1024)
        *(float4*)(sW + i) = *(const float4*)(Wout + i);

    const int wave = t >> 6, lane = t & 63;
    const int g = lane >> 4, tl = lane & 15;   // edge-group, channel-lane
    const float bo = bout[lane];
    __syncthreads();   // the ONLY block-wide barrier

    for (int n = blockIdx.x * 4 + wave; n < N; n += gridDim.x * 4) {
        const int e0 = row_ptr[n];
        const int e1 = row_ptr[n + 1];
        const int cnt = e1 - e0;

        float l = 0.f;
        float4 ctx = make_float4(0.f, 0.f, 0.f, 0.f);
        const uint4 qpk = *(const uint4*)(packed + (size_t)n * 256 + tl * 16);
        const h2 q0 = __builtin_bit_cast(h2, qpk.x);
        const h2 q1 = __builtin_bit_cast(h2, qpk.y);

        if (cnt <= 64) {
            // ---- hot path: 2-deep pipelined gathers, p staged in LDS ----
            int sid = 0;
            if (e0 + lane < e1) sid = senders[e0 + lane];   // coalesced
            const int iters = (cnt + 3) >> 2;
            // Prologue: issue iteration 0's gather (tail lanes clamp to row 0).
            const int s0 = __shfl(sid, g, 64);
            uint4 pk = *(const uint4*)(packed + (size_t)s0 * 256 + tl * 16);
            for (int i = 0; i < iters; ++i) {
                // Issue next gather BEFORE consuming current (2 in flight).
                uint4 pkn = pk;
                if (i + 1 < iters) {                 // wave-uniform branch
                    const int sn = __shfl(sid, (i + 1) * 4 + g, 64);
                    pkn = *(const uint4*)(packed + (size_t)sn * 256 + tl * 16);
                }
                const int idx = i * 4 + g;           // this group's edge
                const h2 k0 = __builtin_bit_cast(h2, pk.x);
                const h2 k1 = __builtin_bit_cast(h2, pk.y);
                const h2 v0 = __builtin_bit_cast(h2, pk.z);
                const h2 v1 = __builtin_bit_cast(h2, pk.w);
                float d = __builtin_amdgcn_fdot2(q0, k0, 0.f, false);
                d = __builtin_amdgcn_fdot2(q1, k1, d, false);
                d += __shfl_xor(d, 1, 64);          // head-group reduce
                d += __shfl_xor(d, 2, 64);
                float p = __expf(d);
                p = (idx < cnt) ? p : 0.f;          // cndmask, no branch
                if ((tl & 3) == 0)
                    sAtt[wave][idx * 4 + (tl >> 2)] = p;   // conflict-free
                l += p;
                ctx.x = fmaf(p, (float)v0.x, ctx.x);
                ctx.y = fmaf(p, (float)v0.y, ctx.y);
                ctx.z = fmaf(p, (float)v1.x, ctx.z);
                ctx.w = fmaf(p, (float)v1.y, ctx.w);
                pk = pkn;
            }
        } else {
            // ---- rare fallback: raw p -> attn_out, normalize in place ----
            for (int base = e0; base < e1; base += 64) {
                const int c2 = min(64, e1 - base);
                int sid2 = 0;
                if (base + lane < e1) sid2 = senders[base + lane];
                const int it2 = (c2 + 3) >> 2;
                for (int i = 0; i < it2; ++i) {
                    const int idx = i * 4 + g;
                    const int s = __shfl(sid2, idx, 64);
                    if (idx < c2) {
                        const uint4 pk =
                            *(const uint4*)(packed + (size_t)s * 256 + tl * 16);
                        const h2 k0 = __builtin_bit_cast(h2, pk.x);
                        const h2 k1 = __builtin_bit_cast(h2, pk.y);
                        const h2 v0 = __builtin_bit_cast(h2, pk.z);
                        const h2 v1 = __builtin_bit_cast(h2, pk.w);
                        float d = __builtin_amdgcn_fdot2(q0, k0, 0.f, false);
                        d = __builtin_amdgcn_fdot2(q1, k1, d, false);
                        d += __shfl_xor(d, 1, 64);
                        d += __shfl_xor(d, 2, 64);
                        const float p = __expf(d);
                        if ((tl & 3) == 0)
                            attn_out[(size_t)(base + idx) * 4 + (tl >> 2)] = p;
                        l += p;
                        ctx.x = fmaf(p, (float)v0.x, ctx.x);
                        ctx.y = fmaf(p, (float)v0.y, ctx.y);
                        ctx.z = fmaf(p, (float)v1.x, ctx.z);
                        ctx.w = fmaf(p, (float)v1.y, ctx.w);
                    }
                }
            }
        }

        // Sum the 4 edge-group partials (butterfly -> all lanes merged).
#pragma unroll
        for (int mask = 16; mask <= 32; mask <<= 1) {
            l     += __shfl_xor(l, mask, 64);
            ctx.x += __shfl_xor(ctx.x, mask, 64);
            ctx.y += __shfl_xor(ctx.y, mask, 64);
            ctx.z += __shfl_xor(ctx.z, mask, 64);
            ctx.w += __shfl_xor(ctx.w, mask, 64);
        }
        const float inv = (l > 0.f) ? (1.f / l) : 0.f;
        if (g == 0) {
            *(float4*)(&sCtx[wave][tl * 4]) =
                make_float4(ctx.x * inv, ctx.y * inv, ctx.z * inv, ctx.w * inv);
        }

        // Pass B: attn = p / l[head], head = f&3 = lane&3 (stride 64).
        const float lh = __shfl(l, (lane & 3) << 2, 64);
        const float invl = (lh > 0.f) ? (1.f / lh) : 0.f;
        if (cnt <= 64) {
            const int cnt4 = cnt * 4;
            for (int f = lane; f < cnt4; f += 64)
                attn_out[e0 * 4 + f] = sAtt[wave][f] * invl;   // wave-local LDS
        } else {
            __builtin_amdgcn_s_waitcnt(0x0F70);   // vmcnt(0): drain raw-p stores
            volatile const float* vp = attn_out;  // L1-bypass
            for (int f = e0 * 4 + lane; f < e1 * 4; f += 64)
                attn_out[f] = vp[f] * invl;
        }

        // Epilogue: out[n][lane] = bout[lane] + sum_k ctx[k]*Wout[k][lane].
        float acc = bo;
#pragma unroll
        for (int k = 0; k < 64; k += 4) {
            const float4 c = *(const float4*)(&sCtx[wave][k]);
            acc = fmaf(c.x, sW[(k + 0) * 64 + lane], acc);
            acc = fmaf(c.y, sW[(k + 1) * 64 + lane], acc);
            acc = fmaf(c.z, sW[(k + 2) * 64 + lane], acc);
            acc = fmaf(c.w, sW[(k + 3) * 64 + lane], acc);
        }
        out[(size_t)n * 64 + lane] = acc;
    }
}

// ---------------------------------------------------------------------------
extern "C" void kernel_launch(void* const* d_in, const int* in_sizes, int n_in,
                              void* d_out, int out_size, void* d_ws, size_t ws_size,
                              hipStream_t stream) {
    const float* nodes   = (const float*)d_in[0];
    const float* W_qk    = (const float*)d_in[1];
    const float* b_qk    = (const float*)d_in[2];
    const float* W_v     = (const float*)d_in[3];
    const float* b_v     = (const float*)d_in[4];
    const float* W_out   = (const float*)d_in[5];
    const float* b_out   = (const float*)d_in[6];
    const int* senders   = (const int*)d_in[7];
    const int* receivers = (const int*)d_in[8];

    const int N = in_sizes[0] / 64;  // 100000
    const int E = in_sizes[7];       // 1000000

    float* out      = (float*)d_out;
    float* attn_out = out + (size_t)N * 64;

    // Workspace: packed fp16 q|v (25.6MB) | rowptr | [spare] | Wt (16KB)
    unsigned char* packed = (unsigned char*)d_ws;
    int*   rowp = (int*)(packed + (size_t)N * 256);
    float* spare = (float*)(rowp + (((N + 1) + 3) & ~3));
    _Float16* Wt = (_Float16*)(spare + (size_t)E * 4);

    const int RB = (N + 1 + 255) / 256;       // rowptr blocks
    mhga_prep<<<32 + RB, 256, 0, stream>>>(W_qk, W_v, Wt, receivers, rowp, N, E);
    mhga_proj<<<(N + 63) / 64, 256, 0, stream>>>(nodes, Wt, b_qk, b_v,
                                                 packed, N);
    // Persistent: 1792 blocks = 7 blocks/CU (LDS 21504 B -> 7 resident);
    // waves grid-stride independently.
    mhga_attn<<<1792, 256, 0, stream>>>(packed, senders, rowp,
                                        W_out, b_out, out, attn_out, N);
}